// Round 2
// baseline (924.588 us; speedup 1.0000x reference)
//
#include <hip/hip_runtime.h>

typedef unsigned short ushortT;
typedef unsigned int uintT;

typedef __bf16 bf16x8 __attribute__((ext_vector_type(8)));
typedef float f32x4 __attribute__((ext_vector_type(4)));

__device__ __forceinline__ ushortT f2bf(float f) {
    union { float f; uintT i; } v; v.f = f;
    uintT r = v.i + 0x7FFFu + ((v.i >> 16) & 1u);   // round-to-nearest-even
    return (ushortT)(r >> 16);
}

__device__ __forceinline__ void gld16(const ushortT* g, ushortT* l) {
    __builtin_amdgcn_global_load_lds(
        (const __attribute__((address_space(1))) void*)g,
        (__attribute__((address_space(3))) void*)l, 16, 0, 0);
}

// ---------------- W0 f32 [1204][256] -> W0T bf16 padded [256][1216] ----------------
__global__ void prep_w(const float* __restrict__ W0, ushortT* __restrict__ W0T) {
    int tid = blockIdx.x * 256 + threadIdx.x;
    if (tid >= 256 * 1216) return;
    int n = tid / 1216, k = tid % 1216;
    ushortT v = 0;
    int kk = -1;
    if (k < 602) kk = k;
    else if (k >= 608 && k < 1210) kk = k - 6;   // second half of concat
    if (kk >= 0) v = f2bf(W0[kk * 256 + n]);
    W0T[n * 1216 + k] = v;
}

// ------- self-features f32 -> bf16 into cat matrix, cols [0,608), pad zero -------
__global__ void copy_pad(const float* __restrict__ src, ushortT* __restrict__ dst, int rows) {
    int tid = blockIdx.x * 256 + threadIdx.x;       // rows*304 pairs
    if (tid >= rows * 304) return;
    int r = tid / 304, p = tid % 304;
    uintT v = 0;
    if (p < 301) {
        float2 f = *(const float2*)&src[(size_t)r * 602 + 2 * p];
        v = (uintT)f2bf(f.x) | ((uintT)f2bf(f.y) << 16);
    }
    *(uintT*)&dst[(size_t)r * 1216 + 2 * p] = v;
}

// ------ neighbor mean (f32 accum) -> bf16 into cat matrix, cols [608,1216) ------
__global__ void agg_mean(const float* __restrict__ src, ushortT* __restrict__ dst,
                         int rows, int fan, float inv) {
    int tid = blockIdx.x * 256 + threadIdx.x;       // rows*304 pairs
    if (tid >= rows * 304) return;
    int r = tid / 304, p = tid % 304;
    uintT v = 0;
    if (p < 301) {
        float s0 = 0.f, s1 = 0.f;
        const float* base = src + (size_t)r * fan * 602 + 2 * p;
        for (int j = 0; j < fan; ++j) {
            float2 f = *(const float2*)&base[(size_t)j * 602];
            s0 += f.x; s1 += f.y;
        }
        v = (uintT)f2bf(s0 * inv) | ((uintT)f2bf(s1 * inv) << 16);
    }
    *(uintT*)&dst[(size_t)r * 1216 + 608 + 2 * p] = v;
}

// --------- 128x128-tile bf16 MFMA GEMM, K=1216, N=256, relu, f32 out ---------
// combined dispatch: blocks [0,blocks1) -> (A1,H1), rest -> (A0,H0)
__global__ __launch_bounds__(256) void gemm_relu(
    const ushortT* __restrict__ A1, const ushortT* __restrict__ A0,
    const ushortT* __restrict__ Bt,
    float* __restrict__ H1, float* __restrict__ H0, int blocks1) {
    __shared__ ushortT sA[128 * 32];
    __shared__ ushortT sB[128 * 32];
    const int K = 1216;
    int bid = blockIdx.x;
    const ushortT* A; float* H; int mt, nt;
    if (bid < blocks1) { A = A1; H = H1; mt = bid >> 1; nt = bid & 1; }
    else { int b = bid - blocks1; A = A0; H = H0; mt = b >> 1; nt = b & 1; }
    int m0 = mt * 128, n0 = nt * 128;
    int t = threadIdx.x, w = t >> 6, l = t & 63;

    // staging: thread t loads 16B; row = t/4, col byte = (t%4)*16
    int srow = t >> 2, scol = (t & 3) * 8;
    const ushortT* Ag0 = A + (size_t)(m0 + srow) * K + scol;
    const ushortT* Ag1 = Ag0 + (size_t)64 * K;
    const ushortT* Bg0 = Bt + (size_t)(n0 + srow) * K + scol;
    const ushortT* Bg1 = Bg0 + (size_t)64 * K;
    ushortT* sAw0 = sA + w * 512;          // wave-uniform LDS bases
    ushortT* sAw1 = sA + 2048 + w * 512;
    ushortT* sBw0 = sB + w * 512;
    ushortT* sBw1 = sB + 2048 + w * 512;

    int wm = w >> 1, wn = w & 1;
    int lm = l & 15, quad = l >> 4;
    int aoff = (wm * 64 + lm) * 32 + quad * 8;
    int boff = (wn * 64 + lm) * 32 + quad * 8;

    f32x4 acc[4][4] = {};
    for (int k0 = 0; k0 < K; k0 += 32) {
        __syncthreads();
        gld16(Ag0 + k0, sAw0);
        gld16(Ag1 + k0, sAw1);
        gld16(Bg0 + k0, sBw0);
        gld16(Bg1 + k0, sBw1);
        __syncthreads();
        bf16x8 af[4], bfr[4];
#pragma unroll
        for (int i = 0; i < 4; ++i) {
            af[i] = *(const bf16x8*)(sA + aoff + i * 512);
            bfr[i] = *(const bf16x8*)(sB + boff + i * 512);
        }
#pragma unroll
        for (int mi = 0; mi < 4; ++mi)
#pragma unroll
            for (int ni = 0; ni < 4; ++ni)
                acc[mi][ni] = __builtin_amdgcn_mfma_f32_16x16x32_bf16(
                    af[mi], bfr[ni], acc[mi][ni], 0, 0, 0);
    }

#pragma unroll
    for (int mi = 0; mi < 4; ++mi) {
        int rb = m0 + wm * 64 + mi * 16 + quad * 4;
#pragma unroll
        for (int ni = 0; ni < 4; ++ni) {
            int c = n0 + wn * 64 + ni * 16 + lm;
            f32x4 v = acc[mi][ni];
#pragma unroll
            for (int r = 0; r < 4; ++r) {
                float x = v[r] > 0.f ? v[r] : 0.f;   // relu
                H[(size_t)(rb + r) * 256 + c] = x;
            }
        }
    }
}

// --------- head: mean25(h1) ++ h0 -> 41 logits -> log_softmax -> f32 out ---------
__global__ __launch_bounds__(64) void final_k(
    const float* __restrict__ H0, const float* __restrict__ H1,
    const float* __restrict__ W1, float* __restrict__ out) {
    __shared__ float xrow[512];
    int r = blockIdx.x;     // 0..1023
    int l = threadIdx.x;    // 0..63
    for (int c = l; c < 256; c += 64)
        xrow[c] = H0[r * 256 + c];
    for (int c = l; c < 256; c += 64) {
        float s = 0.f;
        const float* base = H1 + (size_t)r * 25 * 256 + c;
        for (int j = 0; j < 25; ++j) s += base[j * 256];
        xrow[256 + c] = s * 0.04f;
    }
    __syncthreads();
    float v = -__builtin_inff();
    if (l < 41) {
        float s = 0.f;
        for (int k = 0; k < 512; ++k)
            s += xrow[k] * W1[k * 41 + l];
        v = s;
    }
    float m = v;
    for (int off = 32; off; off >>= 1) m = fmaxf(m, __shfl_xor(m, off, 64));
    float e = (l < 41) ? __expf(v - m) : 0.f;
    float sum = e;
    for (int off = 32; off; off >>= 1) sum += __shfl_xor(sum, off, 64);
    float lse = __logf(sum);
    if (l < 41) out[r * 41 + l] = (v - m) - lse;
}

extern "C" void kernel_launch(void* const* d_in, const int* in_sizes, int n_in,
                              void* d_out, int out_size, void* d_ws, size_t ws_size,
                              hipStream_t stream) {
    const float* x0 = (const float*)d_in[0];   // [1024][602]
    const float* x1 = (const float*)d_in[1];   // [25600][602]
    const float* x2 = (const float*)d_in[2];   // [256000][602]
    const float* W0 = (const float*)d_in[3];   // [1204][256]
    const float* W1 = (const float*)d_in[4];   // [512][41]
    float* out = (float*)d_out;                // [1024][41]
    char* ws = (char*)d_ws;

    ushortT* X1cat = (ushortT*)(ws);                // 25600*1216*2 = 62,259,200
    ushortT* X0cat = (ushortT*)(ws + 62259200);     //  1024*1216*2 =  2,490,368
    ushortT* W0T   = (ushortT*)(ws + 64749568);     //   256*1216*2 =    622,592
    float*   h1    = (float*)(ws + 65372160);       // 25600*256*4  = 26,214,400
    float*   h0    = (float*)(ws + 91586560);       //  1024*256*4  =  1,048,576
                                                    // total ~92.6 MB

    prep_w<<<(256 * 1216 + 255) / 256, 256, 0, stream>>>(W0, W0T);
    copy_pad<<<(25600 * 304 + 255) / 256, 256, 0, stream>>>(x1, X1cat, 25600);
    copy_pad<<<(1024 * 304 + 255) / 256, 256, 0, stream>>>(x0, X0cat, 1024);
    agg_mean<<<(25600 * 304 + 255) / 256, 256, 0, stream>>>(x2, X1cat, 25600, 10, 0.1f);
    agg_mean<<<(1024 * 304 + 255) / 256, 256, 0, stream>>>(x1, X0cat, 1024, 25, 0.04f);
    gemm_relu<<<400 + 16, 256, 0, stream>>>(X1cat, X0cat, W0T, h1, h0, 400);
    final_k<<<1024, 64, 0, stream>>>(h0, h1, W1, out);
}